// Round 13
// baseline (130.649 us; speedup 1.0000x reference)
//
#include <hip/hip_runtime.h>
#include <math.h>

#define EPSF 1e-7f

constexpr int Bb = 2, Nn = 2048, Dd = 512, Hh = 8, HD = 64, KK = 32;
constexpr int ROWS = Bb * Nn; // 4096

typedef __attribute__((ext_vector_type(8))) short bf16x8;
typedef __attribute__((ext_vector_type(4))) float f32x4;
typedef __attribute__((ext_vector_type(8))) unsigned short u16x8;
typedef unsigned long long u64;

__device__ inline unsigned short f2bf(float f) {
    union { float f; unsigned int u; } v; v.f = f;
    unsigned int u = v.u;
    unsigned int r = (u + 0x7fffu + ((u >> 16) & 1u)) >> 16; // RNE
    return (unsigned short)r;
}

__device__ inline float bf2f(short s) {
    union { unsigned int u; float f; } x;
    x.u = ((unsigned int)(unsigned short)s) << 16;
    return x.f;
}

__device__ inline float gelu_tanh(float v) {
    float u = v + 0.044715f * v * v * v;
    return 0.5f * v * (1.f + tanhf(0.79788456080286535588f * u));
}

// ---------------- transpose+cvt device body (uses caller's LDS tile) ----------------
__device__ __forceinline__ void tcvt(float (*tile)[65], const float* __restrict__ in,
                                     unsigned short* __restrict__ out,
                                     int K, int N, int bx, int by) {
    int k0 = by * 64, n0 = bx * 64;
    int t = threadIdx.x;
    int lr = t >> 6, lc = t & 63;
#pragma unroll 4
    for (int p = 0; p < 16; ++p) {
        int r = p * 4 + lr;
        tile[r][lc] = in[(size_t)(k0 + r) * N + n0 + lc];
    }
    __syncthreads();
#pragma unroll 4
    for (int p = 0; p < 16; ++p) {
        int n = p * 4 + lr;
        out[(size_t)(n0 + n) * K + k0 + lc] = f2bf(tile[lc][n]);
    }
}

// ---------------- LayerNorm row body (f32 in): one wave per row, bf16 out ----------------
__device__ __forceinline__ void ln_row(const float* __restrict__ x,
                                       const float* __restrict__ g,
                                       const float* __restrict__ b,
                                       unsigned short* __restrict__ out,
                                       int row, int lane) {
    const float* xr = x + (size_t)row * Dd;
    float4 v0 = *(const float4*)(xr + lane * 8);
    float4 v1 = *(const float4*)(xr + lane * 8 + 4);
    float s = v0.x + v0.y + v0.z + v0.w + v1.x + v1.y + v1.z + v1.w;
    float s2 = v0.x * v0.x + v0.y * v0.y + v0.z * v0.z + v0.w * v0.w +
               v1.x * v1.x + v1.y * v1.y + v1.z * v1.z + v1.w * v1.w;
    for (int o = 32; o; o >>= 1) { s += __shfl_xor(s, o); s2 += __shfl_xor(s2, o); }
    float mean = s * (1.f / Dd);
    float var = s2 * (1.f / Dd) - mean * mean;
    float rstd = rsqrtf(var + 1e-6f);
    float4 g0 = *(const float4*)(g + lane * 8);
    float4 g1v = *(const float4*)(g + lane * 8 + 4);
    float4 b0 = *(const float4*)(b + lane * 8);
    float4 b1v = *(const float4*)(b + lane * 8 + 4);
    u16x8 o;
    o[0] = f2bf((v0.x - mean) * rstd * g0.x + b0.x);
    o[1] = f2bf((v0.y - mean) * rstd * g0.y + b0.y);
    o[2] = f2bf((v0.z - mean) * rstd * g0.z + b0.z);
    o[3] = f2bf((v0.w - mean) * rstd * g0.w + b0.w);
    o[4] = f2bf((v1.x - mean) * rstd * g1v.x + b1v.x);
    o[5] = f2bf((v1.y - mean) * rstd * g1v.y + b1v.y);
    o[6] = f2bf((v1.z - mean) * rstd * g1v.z + b1v.z);
    o[7] = f2bf((v1.w - mean) * rstd * g1v.w + b1v.w);
    *(u16x8*)(out + (size_t)row * Dd + lane * 8) = o;
}

// ---------------- LayerNorm, bf16 input variant (for x1) ----------------
__global__ __launch_bounds__(256) void ln_bf_kernel(const unsigned short* __restrict__ x,
                                                    const float* __restrict__ g,
                                                    const float* __restrict__ b,
                                                    unsigned short* __restrict__ out) {
    int row = blockIdx.x * 4 + (threadIdx.x >> 6);
    int lane = threadIdx.x & 63;
    u16x8 v = *(const u16x8*)(x + (size_t)row * Dd + lane * 8);
    float f[8];
#pragma unroll
    for (int j = 0; j < 8; ++j) f[j] = bf2f((short)v[j]);
    float s = 0.f, s2 = 0.f;
#pragma unroll
    for (int j = 0; j < 8; ++j) { s += f[j]; s2 = fmaf(f[j], f[j], s2); }
    for (int o = 32; o; o >>= 1) { s += __shfl_xor(s, o); s2 += __shfl_xor(s2, o); }
    float mean = s * (1.f / Dd);
    float var = s2 * (1.f / Dd) - mean * mean;
    float rstd = rsqrtf(var + 1e-6f);
    float4 g0 = *(const float4*)(g + lane * 8);
    float4 g1v = *(const float4*)(g + lane * 8 + 4);
    float4 b0 = *(const float4*)(b + lane * 8);
    float4 b1v = *(const float4*)(b + lane * 8 + 4);
    float gg[8] = {g0.x, g0.y, g0.z, g0.w, g1v.x, g1v.y, g1v.z, g1v.w};
    float bb[8] = {b0.x, b0.y, b0.z, b0.w, b1v.x, b1v.y, b1v.z, b1v.w};
    u16x8 o;
#pragma unroll
    for (int j = 0; j < 8; ++j) o[j] = f2bf((f[j] - mean) * rstd * gg[j] + bb[j]);
    *(u16x8*)(out + (size_t)row * Dd + lane * 8) = o;
}

// ---------------- DPP helpers ----------------
template <int CTRL>
__device__ inline float dpp_f(float v) {
    int i = __float_as_int(v);
    i = __builtin_amdgcn_update_dpp(i, i, CTRL, 0xF, 0xF, false);
    return __int_as_float(i);
}
template <int CTRL>
__device__ inline unsigned dpp_u(unsigned v) {
    return (unsigned)__builtin_amdgcn_update_dpp((int)v, (int)v, CTRL, 0xF, 0xF, false);
}

__device__ inline float wave_min_f32(float v) {
    v = fminf(v, dpp_f<0xB1>(v));   // xor1
    v = fminf(v, dpp_f<0x4E>(v));   // xor2
    v = fminf(v, dpp_f<0x141>(v));  // xor7 (row_half_mirror)
    v = fminf(v, dpp_f<0x140>(v));  // xor15 (row_mirror)
    v = fminf(v, __shfl_xor(v, 16));
    v = fminf(v, __shfl_xor(v, 32));
    return v;
}
__device__ inline unsigned wave_min_u32(unsigned v) {
    unsigned o;
    o = dpp_u<0xB1>(v);  v = o < v ? o : v;
    o = dpp_u<0x4E>(v);  v = o < v ? o : v;
    o = dpp_u<0x141>(v); v = o < v ? o : v;
    o = dpp_u<0x140>(v); v = o < v ? o : v;
    o = __shfl_xor(v, 16); v = o < v ? o : v;
    o = __shfl_xor(v, 32); v = o < v ? o : v;
    return v;
}

// ---------------- top-K body: one WAVE per query (smem carved from caller) ----------------
__device__ __forceinline__ void topk_body(char* smem, const float* __restrict__ pos,
                                          const float* __restrict__ cp,
                                          int* __restrict__ idx_out, int bid) {
    float* s_px = (float*)smem;
    float* s_py = s_px + Nn;
    float* s_pz = s_py + Nn;
    float* s_u  = s_pz + Nn;           // c*y2
    int* s_out  = (int*)(s_u + Nn);    // [4][KK]
    int b = bid >> 9;
    int q0 = (bid & 511) * 4;
    int t = threadIdx.x;
    float c = *cp;
    const float* pb = pos + (size_t)b * Nn * 3;
    for (int j = t; j < Nn; j += 256) {
        float px = pb[j * 3 + 0], py = pb[j * 3 + 1], pz = pb[j * 3 + 2];
        s_px[j] = px; s_py[j] = py; s_pz[j] = pz;
        s_u[j] = c * (px * px + py * py + pz * pz);
    }
    __syncthreads();
    int wave = t >> 6, lane = t & 63;
    int n = q0 + wave;
    float qx = s_px[n], qy = s_py[n], qz = s_pz[n];
    float cx2 = s_u[n];
    float x2 = cx2 / c;
    float B = 1.f - cx2;
    float rc = 1.f / c;
    float B2rc = B * B * rc;
    float m2c = -2.f * c;
    float m2B = -2.f * B;
    float key[32];
#pragma unroll
    for (int i = 0; i < 32; ++i) {
        int j = i * 64 + lane;
        float dot = qx * s_px[j] + qy * s_py[j] + qz * s_pz[j];
        float su = s_u[j];
        float r = fmaf(m2c, dot, 1.f);
        float A = r + su;
        float den = fmaf(cx2, su, r);
        float p1 = x2 * A;
        float q1 = A * dot;
        float t1 = fmaf(m2B, q1, B2rc * su);
        float num2 = fmaf(p1, A, t1);
        float rd = __builtin_amdgcn_rcpf(den);
        key[i] = fmaf(num2, rd * rd, 1.0f);  // biased positive
    }
    const u64 MAXK = ~0ull;
    u64 B0 = MAXK, B1 = MAXK, B2 = MAXK, B3 = MAXK;
#pragma unroll
    for (int i = 0; i < 32; ++i) {
        u64 k = ((u64)__float_as_uint(key[i]) << 32) | (unsigned int)(i * 64 + lane);
        if (k < B3) {
            B3 = k;
            if (B3 < B2) { u64 tmp = B2; B2 = B3; B3 = tmp; }
            if (B2 < B1) { u64 tmp = B1; B1 = B2; B2 = tmp; }
            if (B1 < B0) { u64 tmp = B0; B0 = B1; B1 = tmp; }
        }
    }
    int bcount = 4, consumed = 0;
    u64 last = 0;
    for (int s2 = 0; s2 < KK; ++s2) {
        bool need = (bcount == 0) && (consumed < 32);
        if (__any(need)) {
            if (need) {
                B0 = MAXK; B1 = MAXK; B2 = MAXK; B3 = MAXK;
#pragma unroll
                for (int i = 0; i < 32; ++i) {
                    u64 k = ((u64)__float_as_uint(key[i]) << 32) | (unsigned int)(i * 64 + lane);
                    if (k > last && k < B3) {
                        B3 = k;
                        if (B3 < B2) { u64 tmp = B2; B2 = B3; B3 = tmp; }
                        if (B2 < B1) { u64 tmp = B1; B1 = B2; B2 = tmp; }
                        if (B1 < B0) { u64 tmp = B0; B0 = B1; B1 = tmp; }
                    }
                }
                int rem = 32 - consumed;
                bcount = rem < 4 ? rem : 4;
            }
        }
        u64 offer = (bcount > 0) ? B0 : MAXK;
        float okey = __uint_as_float((unsigned)(offer >> 32)); // NaN if exhausted
        unsigned oidx = (unsigned)offer;
        float m = wave_min_f32(okey);
        u64 mask = __ballot(okey == m);
        unsigned gidx;
        if (__popcll(mask) == 1) {
            gidx = (unsigned)__shfl((int)oidx, __ffsll(mask) - 1);
        } else {
            unsigned cand = ((mask >> lane) & 1ull) ? oidx : 0xFFFFFFFFu;
            gidx = wave_min_u32(cand);
        }
        if (lane == 0) s_out[wave * KK + s2] = (int)gidx;
        if (okey == m && oidx == gidx) {
            B0 = B1; B1 = B2; B2 = B3; B3 = MAXK;
            --bcount; ++consumed;
            last = ((u64)__float_as_uint(m) << 32) | gidx;
        }
    }
    if (lane < KK) idx_out[(size_t)(b * Nn + n) * KK + lane] = s_out[wave * KK + lane];
}

// ---------------- fused prologue + topk (independent work, one dispatch) ----------------
__global__ __launch_bounds__(256, 4) void prep_topk_kernel(
    const float* __restrict__ Wq, const float* __restrict__ Wk,
    const float* __restrict__ Wv, const float* __restrict__ Wo,
    const float* __restrict__ Wf1, const float* __restrict__ Wf2,
    const float* __restrict__ bq, const float* __restrict__ bk, const float* __restrict__ bv,
    const float* __restrict__ x, const float* __restrict__ g1, const float* __restrict__ b1,
    unsigned short* __restrict__ wqkv_t, unsigned short* __restrict__ wo_t,
    unsigned short* __restrict__ wf1_t, unsigned short* __restrict__ wf2_t,
    float* __restrict__ bqkv, unsigned short* __restrict__ xn,
    const float* __restrict__ pos, const float* __restrict__ cp, int* __restrict__ idx_out) {
    __shared__ __align__(16) char smem[33280];
    int bid = blockIdx.x;
    if (bid >= 1798) {
        topk_body(smem, pos, cp, idx_out, bid - 1798);
        return;
    }
    float (*tile)[65] = (float (*)[65])smem;
    if (bid < 256) {
        int z = bid >> 6, r = bid & 63;
        const float* in = (z == 0) ? Wq : (z == 1) ? Wk : (z == 2) ? Wv : Wo;
        unsigned short* out = (z == 0) ? wqkv_t : (z == 1) ? wqkv_t + 262144
                            : (z == 2) ? wqkv_t + 524288 : wo_t;
        tcvt(tile, in, out, 512, 512, r & 7, r >> 3);
    } else if (bid < 512) {
        int r = bid - 256;
        tcvt(tile, Wf1, wf1_t, 512, 2048, r & 31, r >> 5);
    } else if (bid < 768) {
        int r = bid - 512;
        tcvt(tile, Wf2, wf2_t, 2048, 512, r & 7, r >> 3);
    } else if (bid < 774) {
        int t = (bid - 768) * 256 + threadIdx.x;
        if (t < 512) bqkv[t] = bq[t];
        else if (t < 1024) bqkv[t] = bk[t - 512];
        else if (t < 1536) bqkv[t] = bv[t - 1024];
    } else {
        ln_row(x, g1, b1, xn, (bid - 774) * 4 + (threadIdx.x >> 6), threadIdx.x & 63);
    }
}

// ---------------- 128x64 bf16 MFMA GEMM, 2-phase prefetch, XOR-swizzled LDS ----------
template <int EPI, int OBF16>
__global__ __launch_bounds__(256) void gemm128x64(const unsigned short* __restrict__ A,
                                                  const unsigned short* __restrict__ Bt,
                                                  const float* __restrict__ bias,
                                                  const float* __restrict__ resid,
                                                  void* __restrict__ C,
                                                  int N, int K, int gridX) {
    __shared__ short As[2 * 128 * 64];
    __shared__ short Bs[2 * 64 * 64];
    int nwg = gridDim.x;
    int cpx = nwg >> 3;
    int wgid = blockIdx.x;
    int nid = (wgid & 7) * cpx + (wgid >> 3);  // bijective XCD swizzle (nwg % 8 == 0)
    int bx = nid % gridX, by = nid / gridX;
    int bm = by * 128, bn = bx * 64;
    int tid = threadIdx.x;
    int wave = tid >> 6, lane = tid & 63;
    int wr = wave >> 1, wc = wave & 1;
    f32x4 acc[4][2] = {};

    int srow = wave * 8 + (lane >> 3);
    int scol = ((lane & 7) ^ (lane >> 3)) * 8;  // pre-swizzled source chunk

#define STAGE(buf, kof)                                                                                   \
    do {                                                                                                  \
        _Pragma("unroll")                                                                                 \
        for (int cc = 0; cc < 4; ++cc) {                                                                  \
            const unsigned short* ga = A + (size_t)(bm + cc * 32 + srow) * K + (kof) + scol;              \
            __builtin_amdgcn_global_load_lds((const __attribute__((address_space(1))) void*)ga,          \
                (__attribute__((address_space(3))) void*)(As + (buf) * 8192 + cc * 2048 + wave * 512),    \
                16, 0, 0);                                                                                \
        }                                                                                                 \
        _Pragma("unroll")                                                                                 \
        for (int cc = 0; cc < 2; ++cc) {                                                                  \
            const unsigned short* gb = Bt + (size_t)(bn + cc * 32 + srow) * K + (kof) + scol;             \
            __builtin_amdgcn_global_load_lds((const __attribute__((address_space(1))) void*)gb,          \
                (__attribute__((address_space(3))) void*)(Bs + (buf) * 4096 + cc * 2048 + wave * 512),    \
                16, 0, 0);                                                                                \
        }                                                                                                 \
    } while (0)

    int nt = K >> 6;
    int cur = 0;
    STAGE(0, 0);
    __syncthreads();
    for (int t = 0; t < nt; ++t) {
        if (t + 1 < nt) STAGE(cur ^ 1, (t + 1) * 64);
        const short* as = As + cur * 8192;
        const short* bs = Bs + cur * 4096;
#pragma unroll
        for (int kk = 0; kk < 64; kk += 32) {
            int kx = (kk + (lane >> 4) * 8) ^ ((lane & 7) << 3);
            bf16x8 af[4], bfr[2];
#pragma unroll
            for (int mi = 0; mi < 4; ++mi)
                af[mi] = *(const bf16x8*)(as + (wr * 64 + mi * 16 + (lane & 15)) * 64 + kx);
#pragma unroll
            for (int ni = 0; ni < 2; ++ni)
                bfr[ni] = *(const bf16x8*)(bs + (wc * 32 + ni * 16 + (lane & 15)) * 64 + kx);
#pragma unroll
            for (int mi = 0; mi < 4; ++mi)
#pragma unroll
                for (int ni = 0; ni < 2; ++ni)
                    acc[mi][ni] = __builtin_amdgcn_mfma_f32_16x16x32_bf16(af[mi], bfr[ni], acc[mi][ni], 0, 0, 0);
        }
        __syncthreads();
        cur ^= 1;
    }
#undef STAGE

    int cbase = bn + wc * 32 + (lane & 15);
    int rbase = bm + wr * 64 + (lane >> 4) * 4;
    float bias_v[2] = {bias[cbase], bias[cbase + 16]};
#pragma unroll
    for (int mi = 0; mi < 4; ++mi) {
#pragma unroll
        for (int r = 0; r < 4; ++r) {
            int row = rbase + mi * 16 + r;
#pragma unroll
            for (int ni = 0; ni < 2; ++ni) {
                int col = cbase + ni * 16;
                float v = acc[mi][ni][r] + bias_v[ni];
                if (EPI == 1) v += resid[(size_t)row * N + col];
                if (EPI == 2) v = gelu_tanh(v);
                if (OBF16) ((unsigned short*)C)[(size_t)row * N + col] = f2bf(v);
                else ((float*)C)[(size_t)row * N + col] = v;
            }
        }
    }
}

// ---------------- 64x64 bf16 MFMA GEMM, 3-slot counted-vmcnt pipeline (T3/T4 minimum) --
// Per iter: STAGE tile t+2 -> s_waitcnt vmcnt(8) (tile t landed, 8 in flight) ->
// raw s_barrier -> compute tile t -> lgkmcnt(0)+barrier (reads done before overwrite).
// Counted vmcnt keeps 2 tiles of loads in flight across barriers (never drains to 0
// mid-loop). Tail: vmcnt(4) then vmcnt(0). RBF16 selects residual dtype.
template <int EPI, int OBF16, int RBF16>
__global__ __launch_bounds__(256) void gemm64(const unsigned short* __restrict__ A,
                                              const unsigned short* __restrict__ Bt,
                                              const float* __restrict__ bias,
                                              const void* __restrict__ resid,
                                              void* __restrict__ C,
                                              int N, int K, int gridX) {
    __shared__ short As[3 * 64 * 64];
    __shared__ short Bs[3 * 64 * 64];
    int nwg = gridDim.x;
    int cpx = nwg >> 3;
    int wgid = blockIdx.x;
    int nid = (wgid & 7) * cpx + (wgid >> 3);
    int bx = nid % gridX, by = nid / gridX;
    int bm = by * 64, bn = bx * 64;
    int tid = threadIdx.x;
    int wave = tid >> 6, lane = tid & 63;
    int wr = wave >> 1, wc = wave & 1;
    f32x4 acc[2][2] = {};

    int srow = wave * 8 + (lane >> 3);
    int scol = ((lane & 7) ^ (lane >> 3)) * 8;
    const unsigned short* gA0 = A + (size_t)(bm + srow) * K + scol;
    const unsigned short* gA1 = A + (size_t)(bm + srow + 32) * K + scol;
    const unsigned short* gB0 = Bt + (size_t)(bn + srow) * K + scol;
    const unsigned short* gB1 = Bt + (size_t)(bn + srow + 32) * K + scol;

#define STAGE(slot, kof)                                                                                \
    do {                                                                                                \
        __builtin_amdgcn_global_load_lds((const __attribute__((address_space(1))) void*)(gA0 + (kof)), \
            (__attribute__((address_space(3))) void*)(As + (slot) * 4096 + wave * 512), 16, 0, 0);      \
        __builtin_amdgcn_global_load_lds((const __attribute__((address_space(1))) void*)(gA1 + (kof)), \
            (__attribute__((address_space(3))) void*)(As + (slot) * 4096 + 2048 + wave * 512), 16, 0, 0);\
        __builtin_amdgcn_global_load_lds((const __attribute__((address_space(1))) void*)(gB0 + (kof)), \
            (__attribute__((address_space(3))) void*)(Bs + (slot) * 4096 + wave * 512), 16, 0, 0);      \
        __builtin_amdgcn_global_load_lds((const __attribute__((address_space(1))) void*)(gB1 + (kof)), \
            (__attribute__((address_space(3))) void*)(Bs + (slot) * 4096 + 2048 + wave * 512), 16, 0, 0);\
    } while (0)

    int nt = K >> 6;                 // >= 8 for all our shapes
    STAGE(0, 0);
    STAGE(1, 64);
    int sc = 0, ss = 2;              // compute slot / stage slot (cycled, no runtime mod)
    for (int t = 0; t < nt; ++t) {
        if (t + 2 < nt) {
            STAGE(ss, (t + 2) * 64);
            asm volatile("s_waitcnt vmcnt(8)" ::: "memory");  // tile t landed; 8 in flight
        } else if (t + 1 < nt) {
            asm volatile("s_waitcnt vmcnt(4)" ::: "memory");  // tile t landed; tile t+1 in flight
        } else {
            asm volatile("s_waitcnt vmcnt(0)" ::: "memory");  // last tile landed
        }
        __builtin_amdgcn_s_barrier();          // all waves' loads for tile t visible
        __builtin_amdgcn_sched_barrier(0);
        const short* as = As + sc * 4096;
        const short* bs = Bs + sc * 4096;
#pragma unroll
        for (int kk = 0; kk < 64; kk += 32) {
            int kx = (kk + (lane >> 4) * 8) ^ ((lane & 7) << 3);
            bf16x8 a0 = *(const bf16x8*)(as + (wr * 32 + (lane & 15)) * 64 + kx);
            bf16x8 a1 = *(const bf16x8*)(as + (wr * 32 + 16 + (lane & 15)) * 64 + kx);
            bf16x8 b0 = *(const bf16x8*)(bs + (wc * 32 + (lane & 15)) * 64 + kx);
            bf16x8 b1 = *(const bf16x8*)(bs + (wc * 32 + 16 + (lane & 15)) * 64 + kx);
            acc[0][0] = __builtin_amdgcn_mfma_f32_16x16x32_bf16(a0, b0, acc[0][0], 0, 0, 0);
            acc[0][1] = __builtin_amdgcn_mfma_f32_16x16x32_bf16(a0, b1, acc[0][1], 0, 0, 0);
            acc[1][0] = __builtin_amdgcn_mfma_f32_16x16x32_bf16(a1, b0, acc[1][0], 0, 0, 0);
            acc[1][1] = __builtin_amdgcn_mfma_f32_16x16x32_bf16(a1, b1, acc[1][1], 0, 0, 0);
        }
        asm volatile("s_waitcnt lgkmcnt(0)" ::: "memory");    // this wave's reads of slot sc done
        __builtin_amdgcn_s_barrier();          // all waves done reading before slot reuse
        sc = (sc == 2) ? 0 : sc + 1;
        ss = (ss == 2) ? 0 : ss + 1;
    }
#undef STAGE

    int cbase = bn + wc * 32 + (lane & 15);
    int rbase = bm + wr * 32 + (lane >> 4) * 4;
    float bias_v[2] = {bias[cbase], bias[cbase + 16]};
#pragma unroll
    for (int mi = 0; mi < 2; ++mi) {
#pragma unroll
        for (int r = 0; r < 4; ++r) {
            int row = rbase + mi * 16 + r;
#pragma unroll
            for (int ni = 0; ni < 2; ++ni) {
                int col = cbase + ni * 16;
                float v = acc[mi][ni][r] + bias_v[ni];
                if (EPI == 1) {
                    if (RBF16) v += bf2f((short)((const unsigned short*)resid)[(size_t)row * N + col]);
                    else v += ((const float*)resid)[(size_t)row * N + col];
                }
                if (EPI == 2) v = gelu_tanh(v);
                if (OBF16) ((unsigned short*)C)[(size_t)row * N + col] = f2bf(v);
                else ((float*)C)[(size_t)row * N + col] = v;
            }
        }
    }
}

// ---------------- fused sparse attention (bf16 qkv, block per query, V reg-prefetch) ----
__global__ __launch_bounds__(256) void attn_kernel(const unsigned short* __restrict__ qkv,
                                                   const int* __restrict__ idx,
                                                   const float* __restrict__ pos,
                                                   const float* __restrict__ Wg,
                                                   const float* __restrict__ bg,
                                                   const float* __restrict__ ascale,
                                                   const float* __restrict__ fscale,
                                                   const float* __restrict__ cp,
                                                   unsigned short* __restrict__ out) {
    constexpr int QS = 1536;
    int bid = blockIdx.x;
    int xcd = bid & 7, slot = bid >> 3;
    int b = xcd >> 2;
    int n = (xcd & 3) * 512 + slot;
    int bn = b * Nn + n;
    int t = threadIdx.x;
    int wave = t >> 6, lane = t & 63;
    __shared__ float s_q[Dd];
    __shared__ float s_geo[KK][3];
    __shared__ int s_idx[KK];
    __shared__ float s_qg[Hh][3];
    __shared__ float s_qb[Hh];
    __shared__ float s_dot[KK][9];
    __shared__ float s_w[Hh][KK];
    __shared__ float s_part[4][Dd];
    float c = *cp;
    if (t >= 64 && t < 96) s_idx[t - 64] = idx[(size_t)bn * KK + (t - 64)];
    if (t < 64) {
        bf16x8 q8 = *(const bf16x8*)(qkv + (size_t)bn * QS + t * 8);
#pragma unroll
        for (int j = 0; j < 8; ++j) s_q[t * 8 + j] = bf2f(q8[j]);
    }
    __syncthreads();
    if (t < KK) {
        const float* qp = pos + (size_t)bn * 3;
        const float* kp = pos + (size_t)(b * Nn + s_idx[t]) * 3;
        float xx = -qp[0], xyc = -qp[1], xz = -qp[2];
        float yx = kp[0], yy = kp[1], yz = kp[2];
        float x2 = xx * xx + xyc * xyc + xz * xz;
        float y2 = yx * yx + yy * yy + yz * yz;
        float xy = xx * yx + xyc * yy + xz * yz;
        float Av = 1.f + 2.f * c * xy + c * y2;
        float Bv = 1.f - c * x2;
        float den = fmaxf(1.f + 2.f * c * xy + c * c * x2 * y2, EPSF);
        float mx = (Av * xx + Bv * yx) / den;
        float my = (Av * xyc + Bv * yy) / den;
        float mz = (Av * xz + Bv * yz) / den;
        float rn = fmaxf(sqrtf(mx * mx + my * my + mz * mz), EPSF);
        float sqrt_c = fmaxf(sqrtf(c), EPSF);
        float max_norm = (1.f - EPSF) / sqrt_c;
        float scpr = fminf(max_norm / rn, 1.f);
        mx *= scpr; my *= scpr; mz *= scpr;
        float yn = sqrtf(mx * mx + my * my + mz * mz);
        if (yn < EPSF) {
            s_geo[t][0] = 0.f; s_geo[t][1] = 0.f; s_geo[t][2] = 0.f;
        } else {
            float syn = fmaxf(yn, EPSF);
            float arg = fminf(sqrt_c * syn, 1.f - EPSF);
            float mag = atanhf(arg) / sqrt_c;
            float f = mag / syn;
            s_geo[t][0] = mx * f; s_geo[t][1] = my * f; s_geo[t][2] = mz * f;
        }
    } else if (t >= 64 && t < 128) {
        int l = t - 64;
        float qg0 = 0.f, qg1 = 0.f, qg2 = 0.f, qbv = 0.f;
#pragma unroll
        for (int j = 0; j < 8; ++j) {
            int d = l * 8 + j;
            float qv = s_q[d];
            qg0 = fmaf(qv, Wg[d], qg0);
            qg1 = fmaf(qv, Wg[512 + d], qg1);
            qg2 = fmaf(qv, Wg[1024 + d], qg2);
            qbv = fmaf(qv, bg[d], qbv);
        }
#pragma unroll
        for (int o = 1; o < 8; o <<= 1) {
            qg0 += __shfl_xor(qg0, o);
            qg1 += __shfl_xor(qg1, o);
            qg2 += __shfl_xor(qg2, o);
            qbv += __shfl_xor(qbv, o);
        }
        if ((l & 7) == 0) {
            int h = l >> 3;
            s_qg[h][0] = qg0;
            s_qg[h][1] = qg1;
            s_qg[h][2] = qg2;
            s_qb[h] = qbv;
        }
    }
    // ---- q.k dots (coalesced row loads) + early V-row prefetch into regs (T14) ----
    bf16x8 v8r[8];
    {
#pragma unroll
        for (int r = 0; r < 8; ++r) {
            int kk = wave * 8 + r;
            int nk = s_idx[kk];
            bf16x8 k8 = *(const bf16x8*)(qkv + (size_t)(b * Nn + nk) * QS + 512 + lane * 8);
            float p = 0.f;
#pragma unroll
            for (int j = 0; j < 8; ++j) p = fmaf(bf2f(k8[j]), s_q[lane * 8 + j], p);
            p += __shfl_xor(p, 1);
            p += __shfl_xor(p, 2);
            p += __shfl_xor(p, 4);
            if ((lane & 7) == 0) s_dot[kk][lane >> 3] = p;
        }
#pragma unroll
        for (int r = 0; r < 8; ++r) {
            int nk = s_idx[wave * 8 + r];
            v8r[r] = *(const bf16x8*)(qkv + (size_t)(b * Nn + nk) * QS + 1024 + lane * 8);
        }
    }
    __syncthreads();
    {
        int h = t >> 5, kk = t & 31;
        float align = s_geo[kk][0] * s_qg[h][0] + s_geo[kk][1] * s_qg[h][1] +
                      s_geo[kk][2] * s_qg[h][2] + s_qb[h];
        float scv = fscale[h] * s_dot[kk][h] * 0.125f + ascale[h] * align;
        float m = scv;
        for (int o = 16; o; o >>= 1) m = fmaxf(m, __shfl_xor(m, o));
        float e = expf(scv - m);
        float ss = e;
        for (int o = 16; o; o >>= 1) ss += __shfl_xor(ss, o);
        s_w[h][kk] = e / ss;
    }
    __syncthreads();
    {
        float acc[8] = {0.f, 0.f, 0.f, 0.f, 0.f, 0.f, 0.f, 0.f};
        int h = lane >> 3;
#pragma unroll
        for (int r = 0; r < 8; ++r) {
            float wgt = s_w[h][wave * 8 + r];
#pragma unroll
            for (int j = 0; j < 8; ++j) acc[j] = fmaf(bf2f(v8r[r][j]), wgt, acc[j]);
        }
#pragma unroll
        for (int j = 0; j < 8; ++j) s_part[wave][lane * 8 + j] = acc[j];
    }
    __syncthreads();
    for (int d = t; d < Dd; d += 256) {
        float s = s_part[0][d] + s_part[1][d] + s_part[2][d] + s_part[3][d];
        out[(size_t)bn * Dd + d] = f2bf(s);
    }
}

extern "C" void kernel_launch(void* const* d_in, const int* in_sizes, int n_in,
                              void* d_out, int out_size, void* d_ws, size_t ws_size,
                              hipStream_t stream) {
    const float* x   = (const float*)d_in[0];
    const float* pos = (const float*)d_in[1];
    const float* cp  = (const float*)d_in[2];
    const float* Wq  = (const float*)d_in[3];
    const float* bq  = (const float*)d_in[4];
    const float* Wk  = (const float*)d_in[5];
    const float* bk  = (const float*)d_in[6];
    const float* Wv  = (const float*)d_in[7];
    const float* bv  = (const float*)d_in[8];
    const float* Wg  = (const float*)d_in[9];
    const float* bg  = (const float*)d_in[10];
    const float* Wo  = (const float*)d_in[11];
    const float* bo  = (const float*)d_in[12];
    const float* Wf1 = (const float*)d_in[13];
    const float* bf1 = (const float*)d_in[14];
    const float* Wf2 = (const float*)d_in[15];
    const float* bf2 = (const float*)d_in[16];
    const float* g1  = (const float*)d_in[17];
    const float* b1  = (const float*)d_in[18];
    const float* g2  = (const float*)d_in[19];
    const float* b2  = (const float*)d_in[20];
    const float* asc = (const float*)d_in[21];
    const float* fsc = (const float*)d_in[22];
    float* out = (float*)d_out;
    char* ws = (char*)d_ws;

    // workspace layout (bytes)
    unsigned short* qkv_bf  = (unsigned short*)(ws + 0);   // 12 MB
    unsigned short* t_bf    = (unsigned short*)(ws + 0);   // 16 MB (aliases qkv after attn)
    unsigned short* xn_bf   = (unsigned short*)(ws + 25165824); // 4 MB (later h)
    unsigned short* x1_bf   = (unsigned short*)(ws + 29360128); // 4 MB (bf16 residual stream)
    unsigned short* attn_bf = (unsigned short*)(ws + 37748736); // 4 MB
    unsigned short* wqkv_t  = (unsigned short*)(ws + 41943040);
    unsigned short* wo_t    = (unsigned short*)(ws + 43515904);
    unsigned short* wf1_t   = (unsigned short*)(ws + 44040192);
    unsigned short* wf2_t   = (unsigned short*)(ws + 46137344);
    int*            idx     = (int*)(ws + 48234496);
    float*          bqkv    = (float*)(ws + 48758784);

    // 1. prologue (weights/bias/LN1) + KNN top-32 fused
    prep_topk_kernel<<<1798 + 1024, 256, 0, stream>>>(
        Wq, Wk, Wv, Wo, Wf1, Wf2, bq, bk, bv, x, g1, b1,
        wqkv_t, wo_t, wf1_t, wf2_t, bqkv, xn_bf, pos, cp, idx);
    // 2. fused QKV GEMM -> bf16 (128x64 tile, 768 blocks)
    gemm128x64<0, 1><<<768, 256, 0, stream>>>(xn_bf, wqkv_t, bqkv, nullptr, qkv_bf, 1536, 512, 24);
    // 3. fused geo + sparse attention -> bf16 (block per query)
    attn_kernel<<<ROWS, 256, 0, stream>>>(qkv_bf, idx, pos, Wg, bg, asc, fsc, cp, attn_bf);
    // 4. x1 = x + attn@Wo + bo  (f32 resid in, bf16 out; 3-slot pipelined gemm64)
    gemm64<1, 1, 0><<<512, 256, 0, stream>>>(attn_bf, wo_t, bo, x, x1_bf, 512, 512, 8);
    // 5. LN2 (bf16 in) -> bf16
    ln_bf_kernel<<<ROWS / 4, 256, 0, stream>>>(x1_bf, g2, b2, xn_bf);
    // 6. FF1 + gelu -> bf16 (128x64 tile, 1024 blocks)
    gemm128x64<2, 1><<<1024, 256, 0, stream>>>(xn_bf, wf1_t, bf1, nullptr, t_bf, 2048, 512, 32);
    // 7. out = x1 + t@Wf2 + bf2 (bf16 resid in, f32 out; 3-slot pipelined gemm64)
    gemm64<1, 0, 1><<<512, 256, 0, stream>>>(t_bf, wf2_t, bf2, x1_bf, out, 512, 2048, 8);
}

// Round 14
// 127.727 us; speedup vs baseline: 1.0229x; 1.0229x over previous
//
#include <hip/hip_runtime.h>
#include <math.h>

#define EPSF 1e-7f

constexpr int Bb = 2, Nn = 2048, Dd = 512, Hh = 8, HD = 64, KK = 32;
constexpr int ROWS = Bb * Nn; // 4096

typedef __attribute__((ext_vector_type(8))) short bf16x8;
typedef __attribute__((ext_vector_type(4))) float f32x4;
typedef __attribute__((ext_vector_type(8))) unsigned short u16x8;
typedef unsigned long long u64;

__device__ inline unsigned short f2bf(float f) {
    union { float f; unsigned int u; } v; v.f = f;
    unsigned int u = v.u;
    unsigned int r = (u + 0x7fffu + ((u >> 16) & 1u)) >> 16; // RNE
    return (unsigned short)r;
}

__device__ inline float bf2f(short s) {
    union { unsigned int u; float f; } x;
    x.u = ((unsigned int)(unsigned short)s) << 16;
    return x.f;
}

__device__ inline float gelu_tanh(float v) {
    float u = v + 0.044715f * v * v * v;
    return 0.5f * v * (1.f + tanhf(0.79788456080286535588f * u));
}

// ---------------- transpose+cvt device body (uses caller's LDS tile) ----------------
__device__ __forceinline__ void tcvt(float (*tile)[65], const float* __restrict__ in,
                                     unsigned short* __restrict__ out,
                                     int K, int N, int bx, int by) {
    int k0 = by * 64, n0 = bx * 64;
    int t = threadIdx.x;
    int lr = t >> 6, lc = t & 63;
#pragma unroll 4
    for (int p = 0; p < 16; ++p) {
        int r = p * 4 + lr;
        tile[r][lc] = in[(size_t)(k0 + r) * N + n0 + lc];
    }
    __syncthreads();
#pragma unroll 4
    for (int p = 0; p < 16; ++p) {
        int n = p * 4 + lr;
        out[(size_t)(n0 + n) * K + k0 + lc] = f2bf(tile[lc][n]);
    }
}

// ---------------- LayerNorm row body (f32 in): one wave per row, bf16 out ----------------
__device__ __forceinline__ void ln_row(const float* __restrict__ x,
                                       const float* __restrict__ g,
                                       const float* __restrict__ b,
                                       unsigned short* __restrict__ out,
                                       int row, int lane) {
    const float* xr = x + (size_t)row * Dd;
    float4 v0 = *(const float4*)(xr + lane * 8);
    float4 v1 = *(const float4*)(xr + lane * 8 + 4);
    float s = v0.x + v0.y + v0.z + v0.w + v1.x + v1.y + v1.z + v1.w;
    float s2 = v0.x * v0.x + v0.y * v0.y + v0.z * v0.z + v0.w * v0.w +
               v1.x * v1.x + v1.y * v1.y + v1.z * v1.z + v1.w * v1.w;
    for (int o = 32; o; o >>= 1) { s += __shfl_xor(s, o); s2 += __shfl_xor(s2, o); }
    float mean = s * (1.f / Dd);
    float var = s2 * (1.f / Dd) - mean * mean;
    float rstd = rsqrtf(var + 1e-6f);
    float4 g0 = *(const float4*)(g + lane * 8);
    float4 g1v = *(const float4*)(g + lane * 8 + 4);
    float4 b0 = *(const float4*)(b + lane * 8);
    float4 b1v = *(const float4*)(b + lane * 8 + 4);
    u16x8 o;
    o[0] = f2bf((v0.x - mean) * rstd * g0.x + b0.x);
    o[1] = f2bf((v0.y - mean) * rstd * g0.y + b0.y);
    o[2] = f2bf((v0.z - mean) * rstd * g0.z + b0.z);
    o[3] = f2bf((v0.w - mean) * rstd * g0.w + b0.w);
    o[4] = f2bf((v1.x - mean) * rstd * g1v.x + b1v.x);
    o[5] = f2bf((v1.y - mean) * rstd * g1v.y + b1v.y);
    o[6] = f2bf((v1.z - mean) * rstd * g1v.z + b1v.z);
    o[7] = f2bf((v1.w - mean) * rstd * g1v.w + b1v.w);
    *(u16x8*)(out + (size_t)row * Dd + lane * 8) = o;
}

// ---------------- LayerNorm, bf16 input variant (for x1) ----------------
__global__ __launch_bounds__(256) void ln_bf_kernel(const unsigned short* __restrict__ x,
                                                    const float* __restrict__ g,
                                                    const float* __restrict__ b,
                                                    unsigned short* __restrict__ out) {
    int row = blockIdx.x * 4 + (threadIdx.x >> 6);
    int lane = threadIdx.x & 63;
    u16x8 v = *(const u16x8*)(x + (size_t)row * Dd + lane * 8);
    float f[8];
#pragma unroll
    for (int j = 0; j < 8; ++j) f[j] = bf2f((short)v[j]);
    float s = 0.f, s2 = 0.f;
#pragma unroll
    for (int j = 0; j < 8; ++j) { s += f[j]; s2 = fmaf(f[j], f[j], s2); }
    for (int o = 32; o; o >>= 1) { s += __shfl_xor(s, o); s2 += __shfl_xor(s2, o); }
    float mean = s * (1.f / Dd);
    float var = s2 * (1.f / Dd) - mean * mean;
    float rstd = rsqrtf(var + 1e-6f);
    float4 g0 = *(const float4*)(g + lane * 8);
    float4 g1v = *(const float4*)(g + lane * 8 + 4);
    float4 b0 = *(const float4*)(b + lane * 8);
    float4 b1v = *(const float4*)(b + lane * 8 + 4);
    float gg[8] = {g0.x, g0.y, g0.z, g0.w, g1v.x, g1v.y, g1v.z, g1v.w};
    float bb[8] = {b0.x, b0.y, b0.z, b0.w, b1v.x, b1v.y, b1v.z, b1v.w};
    u16x8 o;
#pragma unroll
    for (int j = 0; j < 8; ++j) o[j] = f2bf((f[j] - mean) * rstd * gg[j] + bb[j]);
    *(u16x8*)(out + (size_t)row * Dd + lane * 8) = o;
}

// ---------------- DPP helpers ----------------
template <int CTRL>
__device__ inline float dpp_f(float v) {
    int i = __float_as_int(v);
    i = __builtin_amdgcn_update_dpp(i, i, CTRL, 0xF, 0xF, false);
    return __int_as_float(i);
}
template <int CTRL>
__device__ inline unsigned dpp_u(unsigned v) {
    return (unsigned)__builtin_amdgcn_update_dpp((int)v, (int)v, CTRL, 0xF, 0xF, false);
}

__device__ inline float wave_min_f32(float v) {
    v = fminf(v, dpp_f<0xB1>(v));   // xor1
    v = fminf(v, dpp_f<0x4E>(v));   // xor2
    v = fminf(v, dpp_f<0x141>(v));  // xor7 (row_half_mirror)
    v = fminf(v, dpp_f<0x140>(v));  // xor15 (row_mirror)
    v = fminf(v, __shfl_xor(v, 16));
    v = fminf(v, __shfl_xor(v, 32));
    return v;
}
__device__ inline unsigned wave_min_u32(unsigned v) {
    unsigned o;
    o = dpp_u<0xB1>(v);  v = o < v ? o : v;
    o = dpp_u<0x4E>(v);  v = o < v ? o : v;
    o = dpp_u<0x141>(v); v = o < v ? o : v;
    o = dpp_u<0x140>(v); v = o < v ? o : v;
    o = __shfl_xor(v, 16); v = o < v ? o : v;
    o = __shfl_xor(v, 32); v = o < v ? o : v;
    return v;
}

// ---------------- top-K body: one WAVE per query (smem carved from caller) ----------------
__device__ __forceinline__ void topk_body(char* smem, const float* __restrict__ pos,
                                          const float* __restrict__ cp,
                                          int* __restrict__ idx_out, int bid) {
    float* s_px = (float*)smem;
    float* s_py = s_px + Nn;
    float* s_pz = s_py + Nn;
    float* s_u  = s_pz + Nn;           // c*y2
    int* s_out  = (int*)(s_u + Nn);    // [4][KK]
    int b = bid >> 9;
    int q0 = (bid & 511) * 4;
    int t = threadIdx.x;
    float c = *cp;
    const float* pb = pos + (size_t)b * Nn * 3;
    for (int j = t; j < Nn; j += 256) {
        float px = pb[j * 3 + 0], py = pb[j * 3 + 1], pz = pb[j * 3 + 2];
        s_px[j] = px; s_py[j] = py; s_pz[j] = pz;
        s_u[j] = c * (px * px + py * py + pz * pz);
    }
    __syncthreads();
    int wave = t >> 6, lane = t & 63;
    int n = q0 + wave;
    float qx = s_px[n], qy = s_py[n], qz = s_pz[n];
    float cx2 = s_u[n];
    float x2 = cx2 / c;
    float B = 1.f - cx2;
    float rc = 1.f / c;
    float B2rc = B * B * rc;
    float m2c = -2.f * c;
    float m2B = -2.f * B;
    float key[32];
#pragma unroll
    for (int i = 0; i < 32; ++i) {
        int j = i * 64 + lane;
        float dot = qx * s_px[j] + qy * s_py[j] + qz * s_pz[j];
        float su = s_u[j];
        float r = fmaf(m2c, dot, 1.f);
        float A = r + su;
        float den = fmaf(cx2, su, r);
        float p1 = x2 * A;
        float q1 = A * dot;
        float t1 = fmaf(m2B, q1, B2rc * su);
        float num2 = fmaf(p1, A, t1);
        float rd = __builtin_amdgcn_rcpf(den);
        key[i] = fmaf(num2, rd * rd, 1.0f);  // biased positive
    }
    const u64 MAXK = ~0ull;
    u64 B0 = MAXK, B1 = MAXK, B2 = MAXK, B3 = MAXK;
#pragma unroll
    for (int i = 0; i < 32; ++i) {
        u64 k = ((u64)__float_as_uint(key[i]) << 32) | (unsigned int)(i * 64 + lane);
        if (k < B3) {
            B3 = k;
            if (B3 < B2) { u64 tmp = B2; B2 = B3; B3 = tmp; }
            if (B2 < B1) { u64 tmp = B1; B1 = B2; B2 = tmp; }
            if (B1 < B0) { u64 tmp = B0; B0 = B1; B1 = tmp; }
        }
    }
    int bcount = 4, consumed = 0;
    u64 last = 0;
    for (int s2 = 0; s2 < KK; ++s2) {
        bool need = (bcount == 0) && (consumed < 32);
        if (__any(need)) {
            if (need) {
                B0 = MAXK; B1 = MAXK; B2 = MAXK; B3 = MAXK;
#pragma unroll
                for (int i = 0; i < 32; ++i) {
                    u64 k = ((u64)__float_as_uint(key[i]) << 32) | (unsigned int)(i * 64 + lane);
                    if (k > last && k < B3) {
                        B3 = k;
                        if (B3 < B2) { u64 tmp = B2; B2 = B3; B3 = tmp; }
                        if (B2 < B1) { u64 tmp = B1; B1 = B2; B2 = tmp; }
                        if (B1 < B0) { u64 tmp = B0; B0 = B1; B1 = tmp; }
                    }
                }
                int rem = 32 - consumed;
                bcount = rem < 4 ? rem : 4;
            }
        }
        u64 offer = (bcount > 0) ? B0 : MAXK;
        float okey = __uint_as_float((unsigned)(offer >> 32)); // NaN if exhausted
        unsigned oidx = (unsigned)offer;
        float m = wave_min_f32(okey);
        u64 mask = __ballot(okey == m);
        unsigned gidx;
        if (__popcll(mask) == 1) {
            gidx = (unsigned)__shfl((int)oidx, __ffsll(mask) - 1);
        } else {
            unsigned cand = ((mask >> lane) & 1ull) ? oidx : 0xFFFFFFFFu;
            gidx = wave_min_u32(cand);
        }
        if (lane == 0) s_out[wave * KK + s2] = (int)gidx;
        if (okey == m && oidx == gidx) {
            B0 = B1; B1 = B2; B2 = B3; B3 = MAXK;
            --bcount; ++consumed;
            last = ((u64)__float_as_uint(m) << 32) | gidx;
        }
    }
    if (lane < KK) idx_out[(size_t)(b * Nn + n) * KK + lane] = s_out[wave * KK + lane];
}

// ---------------- fused prologue + topk (independent work, one dispatch) ----------------
__global__ __launch_bounds__(256, 4) void prep_topk_kernel(
    const float* __restrict__ Wq, const float* __restrict__ Wk,
    const float* __restrict__ Wv, const float* __restrict__ Wo,
    const float* __restrict__ Wf1, const float* __restrict__ Wf2,
    const float* __restrict__ bq, const float* __restrict__ bk, const float* __restrict__ bv,
    const float* __restrict__ x, const float* __restrict__ g1, const float* __restrict__ b1,
    unsigned short* __restrict__ wqkv_t, unsigned short* __restrict__ wo_t,
    unsigned short* __restrict__ wf1_t, unsigned short* __restrict__ wf2_t,
    float* __restrict__ bqkv, unsigned short* __restrict__ xn,
    const float* __restrict__ pos, const float* __restrict__ cp, int* __restrict__ idx_out) {
    __shared__ __align__(16) char smem[33280];
    int bid = blockIdx.x;
    if (bid >= 1798) {
        topk_body(smem, pos, cp, idx_out, bid - 1798);
        return;
    }
    float (*tile)[65] = (float (*)[65])smem;
    if (bid < 256) {
        int z = bid >> 6, r = bid & 63;
        const float* in = (z == 0) ? Wq : (z == 1) ? Wk : (z == 2) ? Wv : Wo;
        unsigned short* out = (z == 0) ? wqkv_t : (z == 1) ? wqkv_t + 262144
                            : (z == 2) ? wqkv_t + 524288 : wo_t;
        tcvt(tile, in, out, 512, 512, r & 7, r >> 3);
    } else if (bid < 512) {
        int r = bid - 256;
        tcvt(tile, Wf1, wf1_t, 512, 2048, r & 31, r >> 5);
    } else if (bid < 768) {
        int r = bid - 512;
        tcvt(tile, Wf2, wf2_t, 2048, 512, r & 7, r >> 3);
    } else if (bid < 774) {
        int t = (bid - 768) * 256 + threadIdx.x;
        if (t < 512) bqkv[t] = bq[t];
        else if (t < 1024) bqkv[t] = bk[t - 512];
        else if (t < 1536) bqkv[t] = bv[t - 1024];
    } else {
        ln_row(x, g1, b1, xn, (bid - 774) * 4 + (threadIdx.x >> 6), threadIdx.x & 63);
    }
}

// ---------------- 128x64 bf16 MFMA GEMM, 2-phase prefetch, XOR-swizzled LDS ----------
template <int EPI, int OBF16>
__global__ __launch_bounds__(256) void gemm128x64(const unsigned short* __restrict__ A,
                                                  const unsigned short* __restrict__ Bt,
                                                  const float* __restrict__ bias,
                                                  const float* __restrict__ resid,
                                                  void* __restrict__ C,
                                                  int N, int K, int gridX) {
    __shared__ short As[2 * 128 * 64];
    __shared__ short Bs[2 * 64 * 64];
    int nwg = gridDim.x;
    int cpx = nwg >> 3;
    int wgid = blockIdx.x;
    int nid = (wgid & 7) * cpx + (wgid >> 3);  // bijective XCD swizzle (nwg % 8 == 0)
    int bx = nid % gridX, by = nid / gridX;
    int bm = by * 128, bn = bx * 64;
    int tid = threadIdx.x;
    int wave = tid >> 6, lane = tid & 63;
    int wr = wave >> 1, wc = wave & 1;
    f32x4 acc[4][2] = {};

    int srow = wave * 8 + (lane >> 3);
    int scol = ((lane & 7) ^ (lane >> 3)) * 8;  // pre-swizzled source chunk

#define STAGE(buf, kof)                                                                                   \
    do {                                                                                                  \
        _Pragma("unroll")                                                                                 \
        for (int cc = 0; cc < 4; ++cc) {                                                                  \
            const unsigned short* ga = A + (size_t)(bm + cc * 32 + srow) * K + (kof) + scol;              \
            __builtin_amdgcn_global_load_lds((const __attribute__((address_space(1))) void*)ga,          \
                (__attribute__((address_space(3))) void*)(As + (buf) * 8192 + cc * 2048 + wave * 512),    \
                16, 0, 0);                                                                                \
        }                                                                                                 \
        _Pragma("unroll")                                                                                 \
        for (int cc = 0; cc < 2; ++cc) {                                                                  \
            const unsigned short* gb = Bt + (size_t)(bn + cc * 32 + srow) * K + (kof) + scol;             \
            __builtin_amdgcn_global_load_lds((const __attribute__((address_space(1))) void*)gb,          \
                (__attribute__((address_space(3))) void*)(Bs + (buf) * 4096 + cc * 2048 + wave * 512),    \
                16, 0, 0);                                                                                \
        }                                                                                                 \
    } while (0)

    int nt = K >> 6;
    int cur = 0;
    STAGE(0, 0);
    __syncthreads();
    for (int t = 0; t < nt; ++t) {
        if (t + 1 < nt) STAGE(cur ^ 1, (t + 1) * 64);
        const short* as = As + cur * 8192;
        const short* bs = Bs + cur * 4096;
#pragma unroll
        for (int kk = 0; kk < 64; kk += 32) {
            int kx = (kk + (lane >> 4) * 8) ^ ((lane & 7) << 3);
            bf16x8 af[4], bfr[2];
#pragma unroll
            for (int mi = 0; mi < 4; ++mi)
                af[mi] = *(const bf16x8*)(as + (wr * 64 + mi * 16 + (lane & 15)) * 64 + kx);
#pragma unroll
            for (int ni = 0; ni < 2; ++ni)
                bfr[ni] = *(const bf16x8*)(bs + (wc * 32 + ni * 16 + (lane & 15)) * 64 + kx);
#pragma unroll
            for (int mi = 0; mi < 4; ++mi)
#pragma unroll
                for (int ni = 0; ni < 2; ++ni)
                    acc[mi][ni] = __builtin_amdgcn_mfma_f32_16x16x32_bf16(af[mi], bfr[ni], acc[mi][ni], 0, 0, 0);
        }
        __syncthreads();
        cur ^= 1;
    }
#undef STAGE

    int cbase = bn + wc * 32 + (lane & 15);
    int rbase = bm + wr * 64 + (lane >> 4) * 4;
    float bias_v[2] = {bias[cbase], bias[cbase + 16]};
#pragma unroll
    for (int mi = 0; mi < 4; ++mi) {
#pragma unroll
        for (int r = 0; r < 4; ++r) {
            int row = rbase + mi * 16 + r;
#pragma unroll
            for (int ni = 0; ni < 2; ++ni) {
                int col = cbase + ni * 16;
                float v = acc[mi][ni][r] + bias_v[ni];
                if (EPI == 1) v += resid[(size_t)row * N + col];
                if (EPI == 2) v = gelu_tanh(v);
                if (OBF16) ((unsigned short*)C)[(size_t)row * N + col] = f2bf(v);
                else ((float*)C)[(size_t)row * N + col] = v;
            }
        }
    }
}

// ---------------- 64x64 bf16 MFMA GEMM, 2-phase prefetch, XOR-swizzled LDS ----------
// (R12's proven form; RBF16 selects residual dtype: 0 = f32, 1 = bf16)
template <int EPI, int OBF16, int RBF16>
__global__ __launch_bounds__(256) void gemm64(const unsigned short* __restrict__ A,
                                              const unsigned short* __restrict__ Bt,
                                              const float* __restrict__ bias,
                                              const void* __restrict__ resid,
                                              void* __restrict__ C,
                                              int N, int K, int gridX) {
    __shared__ short As[2 * 64 * 64];
    __shared__ short Bs[2 * 64 * 64];
    int nwg = gridDim.x;
    int cpx = nwg >> 3;
    int wgid = blockIdx.x;
    int nid = (wgid & 7) * cpx + (wgid >> 3);
    int bx = nid % gridX, by = nid / gridX;
    int bm = by * 64, bn = bx * 64;
    int tid = threadIdx.x;
    int wave = tid >> 6, lane = tid & 63;
    int wr = wave >> 1, wc = wave & 1;
    f32x4 acc[2][2] = {};

    int srow = wave * 8 + (lane >> 3);
    int scol = ((lane & 7) ^ (lane >> 3)) * 8;
    const unsigned short* gA0 = A + (size_t)(bm + srow) * K + scol;
    const unsigned short* gA1 = A + (size_t)(bm + srow + 32) * K + scol;
    const unsigned short* gB0 = Bt + (size_t)(bn + srow) * K + scol;
    const unsigned short* gB1 = Bt + (size_t)(bn + srow + 32) * K + scol;

#define STAGE(buf, kof)                                                                                 \
    do {                                                                                                \
        __builtin_amdgcn_global_load_lds((const __attribute__((address_space(1))) void*)(gA0 + (kof)), \
            (__attribute__((address_space(3))) void*)(As + (buf) * 4096 + wave * 512), 16, 0, 0);       \
        __builtin_amdgcn_global_load_lds((const __attribute__((address_space(1))) void*)(gA1 + (kof)), \
            (__attribute__((address_space(3))) void*)(As + (buf) * 4096 + 2048 + wave * 512), 16, 0, 0);\
        __builtin_amdgcn_global_load_lds((const __attribute__((address_space(1))) void*)(gB0 + (kof)), \
            (__attribute__((address_space(3))) void*)(Bs + (buf) * 4096 + wave * 512), 16, 0, 0);       \
        __builtin_amdgcn_global_load_lds((const __attribute__((address_space(1))) void*)(gB1 + (kof)), \
            (__attribute__((address_space(3))) void*)(Bs + (buf) * 4096 + 2048 + wave * 512), 16, 0, 0);\
    } while (0)

    int nt = K >> 6;
    int cur = 0;
    STAGE(0, 0);
    __syncthreads();
    for (int t = 0; t < nt; ++t) {
        if (t + 1 < nt) STAGE(cur ^ 1, (t + 1) * 64);
        const short* as = As + cur * 4096;
        const short* bs = Bs + cur * 4096;
#pragma unroll
        for (int kk = 0; kk < 64; kk += 32) {
            int kx = (kk + (lane >> 4) * 8) ^ ((lane & 7) << 3);
            bf16x8 a0 = *(const bf16x8*)(as + (wr * 32 + (lane & 15)) * 64 + kx);
            bf16x8 a1 = *(const bf16x8*)(as + (wr * 32 + 16 + (lane & 15)) * 64 + kx);
            bf16x8 b0 = *(const bf16x8*)(bs + (wc * 32 + (lane & 15)) * 64 + kx);
            bf16x8 b1 = *(const bf16x8*)(bs + (wc * 32 + 16 + (lane & 15)) * 64 + kx);
            acc[0][0] = __builtin_amdgcn_mfma_f32_16x16x32_bf16(a0, b0, acc[0][0], 0, 0, 0);
            acc[0][1] = __builtin_amdgcn_mfma_f32_16x16x32_bf16(a0, b1, acc[0][1], 0, 0, 0);
            acc[1][0] = __builtin_amdgcn_mfma_f32_16x16x32_bf16(a1, b0, acc[1][0], 0, 0, 0);
            acc[1][1] = __builtin_amdgcn_mfma_f32_16x16x32_bf16(a1, b1, acc[1][1], 0, 0, 0);
        }
        __syncthreads();
        cur ^= 1;
    }
#undef STAGE

    int cbase = bn + wc * 32 + (lane & 15);
    int rbase = bm + wr * 32 + (lane >> 4) * 4;
    float bias_v[2] = {bias[cbase], bias[cbase + 16]};
#pragma unroll
    for (int mi = 0; mi < 2; ++mi) {
#pragma unroll
        for (int r = 0; r < 4; ++r) {
            int row = rbase + mi * 16 + r;
#pragma unroll
            for (int ni = 0; ni < 2; ++ni) {
                int col = cbase + ni * 16;
                float v = acc[mi][ni][r] + bias_v[ni];
                if (EPI == 1) {
                    if (RBF16) v += bf2f((short)((const unsigned short*)resid)[(size_t)row * N + col]);
                    else v += ((const float*)resid)[(size_t)row * N + col];
                }
                if (EPI == 2) v = gelu_tanh(v);
                if (OBF16) ((unsigned short*)C)[(size_t)row * N + col] = f2bf(v);
                else ((float*)C)[(size_t)row * N + col] = v;
            }
        }
    }
}

// ---------------- fused sparse attention (bf16 qkv, block per query, V reg-prefetch) ----
__global__ __launch_bounds__(256) void attn_kernel(const unsigned short* __restrict__ qkv,
                                                   const int* __restrict__ idx,
                                                   const float* __restrict__ pos,
                                                   const float* __restrict__ Wg,
                                                   const float* __restrict__ bg,
                                                   const float* __restrict__ ascale,
                                                   const float* __restrict__ fscale,
                                                   const float* __restrict__ cp,
                                                   unsigned short* __restrict__ out) {
    constexpr int QS = 1536;
    int bid = blockIdx.x;
    int xcd = bid & 7, slot = bid >> 3;
    int b = xcd >> 2;
    int n = (xcd & 3) * 512 + slot;
    int bn = b * Nn + n;
    int t = threadIdx.x;
    int wave = t >> 6, lane = t & 63;
    __shared__ float s_q[Dd];
    __shared__ float s_geo[KK][3];
    __shared__ int s_idx[KK];
    __shared__ float s_qg[Hh][3];
    __shared__ float s_qb[Hh];
    __shared__ float s_dot[KK][9];
    __shared__ float s_w[Hh][KK];
    __shared__ float s_part[4][Dd];
    float c = *cp;
    if (t >= 64 && t < 96) s_idx[t - 64] = idx[(size_t)bn * KK + (t - 64)];
    if (t < 64) {
        bf16x8 q8 = *(const bf16x8*)(qkv + (size_t)bn * QS + t * 8);
#pragma unroll
        for (int j = 0; j < 8; ++j) s_q[t * 8 + j] = bf2f(q8[j]);
    }
    __syncthreads();
    if (t < KK) {
        const float* qp = pos + (size_t)bn * 3;
        const float* kp = pos + (size_t)(b * Nn + s_idx[t]) * 3;
        float xx = -qp[0], xyc = -qp[1], xz = -qp[2];
        float yx = kp[0], yy = kp[1], yz = kp[2];
        float x2 = xx * xx + xyc * xyc + xz * xz;
        float y2 = yx * yx + yy * yy + yz * yz;
        float xy = xx * yx + xyc * yy + xz * yz;
        float Av = 1.f + 2.f * c * xy + c * y2;
        float Bv = 1.f - c * x2;
        float den = fmaxf(1.f + 2.f * c * xy + c * c * x2 * y2, EPSF);
        float mx = (Av * xx + Bv * yx) / den;
        float my = (Av * xyc + Bv * yy) / den;
        float mz = (Av * xz + Bv * yz) / den;
        float rn = fmaxf(sqrtf(mx * mx + my * my + mz * mz), EPSF);
        float sqrt_c = fmaxf(sqrtf(c), EPSF);
        float max_norm = (1.f - EPSF) / sqrt_c;
        float scpr = fminf(max_norm / rn, 1.f);
        mx *= scpr; my *= scpr; mz *= scpr;
        float yn = sqrtf(mx * mx + my * my + mz * mz);
        if (yn < EPSF) {
            s_geo[t][0] = 0.f; s_geo[t][1] = 0.f; s_geo[t][2] = 0.f;
        } else {
            float syn = fmaxf(yn, EPSF);
            float arg = fminf(sqrt_c * syn, 1.f - EPSF);
            float mag = atanhf(arg) / sqrt_c;
            float f = mag / syn;
            s_geo[t][0] = mx * f; s_geo[t][1] = my * f; s_geo[t][2] = mz * f;
        }
    } else if (t >= 64 && t < 128) {
        int l = t - 64;
        float qg0 = 0.f, qg1 = 0.f, qg2 = 0.f, qbv = 0.f;
#pragma unroll
        for (int j = 0; j < 8; ++j) {
            int d = l * 8 + j;
            float qv = s_q[d];
            qg0 = fmaf(qv, Wg[d], qg0);
            qg1 = fmaf(qv, Wg[512 + d], qg1);
            qg2 = fmaf(qv, Wg[1024 + d], qg2);
            qbv = fmaf(qv, bg[d], qbv);
        }
#pragma unroll
        for (int o = 1; o < 8; o <<= 1) {
            qg0 += __shfl_xor(qg0, o);
            qg1 += __shfl_xor(qg1, o);
            qg2 += __shfl_xor(qg2, o);
            qbv += __shfl_xor(qbv, o);
        }
        if ((l & 7) == 0) {
            int h = l >> 3;
            s_qg[h][0] = qg0;
            s_qg[h][1] = qg1;
            s_qg[h][2] = qg2;
            s_qb[h] = qbv;
        }
    }
    // ---- q.k dots (coalesced row loads) + early V-row prefetch into regs (T14) ----
    bf16x8 v8r[8];
    {
#pragma unroll
        for (int r = 0; r < 8; ++r) {
            int kk = wave * 8 + r;
            int nk = s_idx[kk];
            bf16x8 k8 = *(const bf16x8*)(qkv + (size_t)(b * Nn + nk) * QS + 512 + lane * 8);
            float p = 0.f;
#pragma unroll
            for (int j = 0; j < 8; ++j) p = fmaf(bf2f(k8[j]), s_q[lane * 8 + j], p);
            p += __shfl_xor(p, 1);
            p += __shfl_xor(p, 2);
            p += __shfl_xor(p, 4);
            if ((lane & 7) == 0) s_dot[kk][lane >> 3] = p;
        }
#pragma unroll
        for (int r = 0; r < 8; ++r) {
            int nk = s_idx[wave * 8 + r];
            v8r[r] = *(const bf16x8*)(qkv + (size_t)(b * Nn + nk) * QS + 1024 + lane * 8);
        }
    }
    __syncthreads();
    {
        int h = t >> 5, kk = t & 31;
        float align = s_geo[kk][0] * s_qg[h][0] + s_geo[kk][1] * s_qg[h][1] +
                      s_geo[kk][2] * s_qg[h][2] + s_qb[h];
        float scv = fscale[h] * s_dot[kk][h] * 0.125f + ascale[h] * align;
        float m = scv;
        for (int o = 16; o; o >>= 1) m = fmaxf(m, __shfl_xor(m, o));
        float e = expf(scv - m);
        float ss = e;
        for (int o = 16; o; o >>= 1) ss += __shfl_xor(ss, o);
        s_w[h][kk] = e / ss;
    }
    __syncthreads();
    {
        float acc[8] = {0.f, 0.f, 0.f, 0.f, 0.f, 0.f, 0.f, 0.f};
        int h = lane >> 3;
#pragma unroll
        for (int r = 0; r < 8; ++r) {
            float wgt = s_w[h][wave * 8 + r];
#pragma unroll
            for (int j = 0; j < 8; ++j) acc[j] = fmaf(bf2f(v8r[r][j]), wgt, acc[j]);
        }
#pragma unroll
        for (int j = 0; j < 8; ++j) s_part[wave][lane * 8 + j] = acc[j];
    }
    __syncthreads();
    for (int d = t; d < Dd; d += 256) {
        float s = s_part[0][d] + s_part[1][d] + s_part[2][d] + s_part[3][d];
        out[(size_t)bn * Dd + d] = f2bf(s);
    }
}

extern "C" void kernel_launch(void* const* d_in, const int* in_sizes, int n_in,
                              void* d_out, int out_size, void* d_ws, size_t ws_size,
                              hipStream_t stream) {
    const float* x   = (const float*)d_in[0];
    const float* pos = (const float*)d_in[1];
    const float* cp  = (const float*)d_in[2];
    const float* Wq  = (const float*)d_in[3];
    const float* bq  = (const float*)d_in[4];
    const float* Wk  = (const float*)d_in[5];
    const float* bk  = (const float*)d_in[6];
    const float* Wv  = (const float*)d_in[7];
    const float* bv  = (const float*)d_in[8];
    const float* Wg  = (const float*)d_in[9];
    const float* bg  = (const float*)d_in[10];
    const float* Wo  = (const float*)d_in[11];
    const float* bo  = (const float*)d_in[12];
    const float* Wf1 = (const float*)d_in[13];
    const float* bf1 = (const float*)d_in[14];
    const float* Wf2 = (const float*)d_in[15];
    const float* bf2 = (const float*)d_in[16];
    const float* g1  = (const float*)d_in[17];
    const float* b1  = (const float*)d_in[18];
    const float* g2  = (const float*)d_in[19];
    const float* b2  = (const float*)d_in[20];
    const float* asc = (const float*)d_in[21];
    const float* fsc = (const float*)d_in[22];
    float* out = (float*)d_out;
    char* ws = (char*)d_ws;

    // workspace layout (bytes)
    unsigned short* qkv_bf  = (unsigned short*)(ws + 0);   // 12 MB
    unsigned short* t_bf    = (unsigned short*)(ws + 0);   // 16 MB (aliases qkv after attn)
    unsigned short* xn_bf   = (unsigned short*)(ws + 25165824); // 4 MB (later h)
    unsigned short* x1_bf   = (unsigned short*)(ws + 29360128); // 4 MB (bf16 residual stream)
    unsigned short* attn_bf = (unsigned short*)(ws + 37748736); // 4 MB
    unsigned short* wqkv_t  = (unsigned short*)(ws + 41943040);
    unsigned short* wo_t    = (unsigned short*)(ws + 43515904);
    unsigned short* wf1_t   = (unsigned short*)(ws + 44040192);
    unsigned short* wf2_t   = (unsigned short*)(ws + 46137344);
    int*            idx     = (int*)(ws + 48234496);
    float*          bqkv    = (float*)(ws + 48758784);

    // 1. prologue (weights/bias/LN1) + KNN top-32 fused
    prep_topk_kernel<<<1798 + 1024, 256, 0, stream>>>(
        Wq, Wk, Wv, Wo, Wf1, Wf2, bq, bk, bv, x, g1, b1,
        wqkv_t, wo_t, wf1_t, wf2_t, bqkv, xn_bf, pos, cp, idx);
    // 2. fused QKV GEMM -> bf16 (128x64 tile, 768 blocks)
    gemm128x64<0, 1><<<768, 256, 0, stream>>>(xn_bf, wqkv_t, bqkv, nullptr, qkv_bf, 1536, 512, 24);
    // 3. fused geo + sparse attention -> bf16 (block per query)
    attn_kernel<<<ROWS, 256, 0, stream>>>(qkv_bf, idx, pos, Wg, bg, asc, fsc, cp, attn_bf);
    // 4. x1 = x + attn@Wo + bo (f32 resid in, bf16 out; 2-phase gemm64)
    gemm64<1, 1, 0><<<512, 256, 0, stream>>>(attn_bf, wo_t, bo, x, x1_bf, 512, 512, 8);
    // 5. LN2 (bf16 in) -> bf16
    ln_bf_kernel<<<ROWS / 4, 256, 0, stream>>>(x1_bf, g2, b2, xn_bf);
    // 6. FF1 + gelu -> bf16 (128x64 tile, 1024 blocks)
    gemm128x64<2, 1><<<1024, 256, 0, stream>>>(xn_bf, wf1_t, bf1, nullptr, t_bf, 2048, 512, 32);
    // 7. out = x1 + t@Wf2 + bf2 (bf16 resid in, f32 out; 2-phase gemm64)
    gemm64<1, 0, 1><<<512, 256, 0, stream>>>(t_bf, wf2_t, bf2, x1_bf, out, 512, 2048, 8);
}